// Round 1
// baseline (1478.070 us; speedup 1.0000x reference)
//
#include <hip/hip_runtime.h>
#include <hip/hip_bf16.h>

#define CATS 17
#define SCALES 5
#define DIM 256
#define NSEG (CATS * SCALES)   // 85
#define TEMP 0.07f

// ---------------------------------------------------------------------------
// Kernel 1: fused segment-sum + segment-count.
// grid = (256 row-chunks, 2 dim-halves), block = 512 threads.
// Each block: LDS accumulator [85][128] f32 (43.5 KB), thread t owns
// dim (t&127) of half h, row-slot (t>>7). LDS atomicAdd handles the rare
// cross-slot same-segment collision. Flush with global fp32 atomics.
// ---------------------------------------------------------------------------
__global__ __launch_bounds__(512, 2)
void seg_sum_kernel(const float* __restrict__ feats,
                    const int* __restrict__ tgt,
                    const int* __restrict__ lvl,
                    float* __restrict__ sums,     // [NSEG][DIM]
                    float* __restrict__ counts,   // [NSEG]
                    int n, int rowsPerChunk) {
    __shared__ float acc[NSEG * 128];
    __shared__ float cntLds[NSEG];

    const int tid  = threadIdx.x;
    const int h    = blockIdx.y;        // dim half: 0 or 1
    const int dl   = tid & 127;         // dim within half
    const int slot = tid >> 7;          // row slot 0..3

    for (int i = tid; i < NSEG * 128; i += 512) acc[i] = 0.f;
    if (tid < NSEG) cntLds[tid] = 0.f;
    __syncthreads();

    const int base = blockIdx.x * rowsPerChunk;
    const int rows = min(rowsPerChunk, n - base);

    const float* fp = feats + (size_t)(base + slot) * DIM + h * 128 + dl;
    const int*   tp = tgt + base + slot;
    const int*   lp = lvl + base + slot;
    const bool countThread = (h == 0) && (dl == 0);

    #pragma unroll 4
    for (int r = slot; r < rows; r += 4) {
        const int   seg = tp[0] * SCALES + lp[0];
        const float v   = fp[0];
        atomicAdd(&acc[seg * 128 + dl], v);
        if (countThread) atomicAdd(&cntLds[seg], 1.f);
        fp += 4 * DIM; tp += 4; lp += 4;
    }
    __syncthreads();

    for (int i = tid; i < NSEG * 128; i += 512) {
        unsafeAtomicAdd(&sums[(size_t)(i >> 7) * DIM + h * 128 + (i & 127)],
                        acc[i]);
    }
    if (h == 0) {
        for (int i = tid; i < NSEG; i += 512)
            unsafeAtomicAdd(&counts[i], cntLds[i]);
    }
}

// ---------------------------------------------------------------------------
// Kernel 2: InfoNCE head. One block (64 lanes) per output row cs = c*5+s.
// logits[k] = <v1[c,s], v2[k,s]> / T with v1,v2 L2-normalized.
// All reductions are intra-wave shuffles; lane 0 does the 17-way logsumexp.
// ---------------------------------------------------------------------------
__global__ void infonce_kernel(const float* __restrict__ protos,  // [NSEG][DIM]
                               const float* __restrict__ sums,    // [NSEG][DIM]
                               const float* __restrict__ counts,  // [NSEG]
                               float* __restrict__ numAcc) {
    const int cs   = blockIdx.x;        // c*SCALES + s
    const int s    = cs % SCALES;
    const int lane = threadIdx.x;       // 0..63, 4 dims each

    const float4 p = *reinterpret_cast<const float4*>(
        protos + (size_t)cs * DIM + lane * 4);
    float ssq1 = p.x * p.x + p.y * p.y + p.z * p.z + p.w * p.w;
    #pragma unroll
    for (int off = 32; off > 0; off >>= 1) ssq1 += __shfl_down(ssq1, off);
    ssq1 = __shfl(ssq1, 0);

    float logits[CATS];
    for (int k = 0; k < CATS; ++k) {
        const int r2 = k * SCALES + s;
        const float cntv = counts[r2];
        float4 dv;
        if (cntv > 0.f) {
            const float4 sm = *reinterpret_cast<const float4*>(
                sums + (size_t)r2 * DIM + lane * 4);
            const float inv = 1.f / cntv;
            dv = make_float4(sm.x * inv, sm.y * inv, sm.z * inv, sm.w * inv);
        } else {
            dv = make_float4(0.01f, 0.01f, 0.01f, 0.01f);
        }
        float ssq2 = dv.x * dv.x + dv.y * dv.y + dv.z * dv.z + dv.w * dv.w;
        float dot  = p.x * dv.x + p.y * dv.y + p.z * dv.z + p.w * dv.w;
        #pragma unroll
        for (int off = 32; off > 0; off >>= 1) {
            ssq2 += __shfl_down(ssq2, off);
            dot  += __shfl_down(dot, off);
        }
        // valid on lane 0; broadcast
        const float lg = dot / (sqrtf(ssq2) * sqrtf(ssq1) * TEMP);
        logits[k] = __shfl(lg, 0);
    }

    if (lane == 0) {
        float m = logits[0];
        #pragma unroll
        for (int k = 1; k < CATS; ++k) m = fmaxf(m, logits[k]);
        float sum = 0.f;
        #pragma unroll
        for (int k = 0; k < CATS; ++k) sum += expf(logits[k] - m);
        const float lse     = m + logf(sum);
        const int   label   = cs % CATS;
        const float per_row = lse - logits[label];
        if (counts[cs] > 0.f) unsafeAtomicAdd(numAcc, per_row);
    }
}

// ---------------------------------------------------------------------------
// Kernel 3: final scalar division.
// ---------------------------------------------------------------------------
__global__ void finalize_kernel(const float* __restrict__ counts,
                                const float* __restrict__ numAcc,
                                float* __restrict__ out) {
    float msum = 0.f;
    for (int i = 0; i < NSEG; ++i) msum += (counts[i] > 0.f) ? 1.f : 0.f;
    out[0] = numAcc[0] / fmaxf(msum, 1.f);
}

extern "C" void kernel_launch(void* const* d_in, const int* in_sizes, int n_in,
                              void* d_out, int out_size, void* d_ws, size_t ws_size,
                              hipStream_t stream) {
    const float* feats  = (const float*)d_in[0];   // [N][256] f32
    const int*   tgt    = (const int*)d_in[1];     // [N] int32
    const int*   lvl    = (const int*)d_in[2];     // [N] int32
    const float* protos = (const float*)d_in[3];   // [17][5][256] f32
    float* out = (float*)d_out;

    float* sums   = (float*)d_ws;          // NSEG*DIM
    float* counts = sums + NSEG * DIM;     // NSEG
    float* numAcc = counts + NSEG;         // 1

    const int n = in_sizes[1];             // N rows

    hipMemsetAsync(d_ws, 0, (size_t)(NSEG * DIM + NSEG + 1) * sizeof(float),
                   stream);

    const int nChunks = 256;
    const int rowsPerChunk = (n + nChunks - 1) / nChunks;
    dim3 g1(nChunks, 2);
    seg_sum_kernel<<<g1, 512, 0, stream>>>(feats, tgt, lvl, sums, counts,
                                           n, rowsPerChunk);
    infonce_kernel<<<NSEG, 64, 0, stream>>>(protos, sums, counts, numAcc);
    finalize_kernel<<<1, 1, 0, stream>>>(counts, numAcc, out);
}

// Round 2
// 1314.782 us; speedup vs baseline: 1.1242x; 1.1242x over previous
//
#include <hip/hip_runtime.h>
#include <hip/hip_bf16.h>

#define CATS 17
#define SCALES 5
#define DIM 256
#define NSEG (CATS * SCALES)   // 85
#define TEMP 0.07f
#define UNR 8                  // loads in flight per wave

// ---------------------------------------------------------------------------
// Kernel 1: fused segment-sum + segment-count.
// grid = (nChunks row-chunks, 2 dim-halves), block = 512 threads.
// Thread t: dl4 = t&31 (which float4 of the 128-dim half), slot = t>>5
// (16 row slots). Each iteration loads a float4 (16B/lane, coalesced 1KB per
// wave instr); manual unroll UNR=8 issues 8 independent loads before any
// LDS atomic -> 8 outstanding loads/wave. LDS accumulator stored as
// [seg][j][dl4] (j = float4 component) so each ds_add_f32 hits banks 0..31
// once per 32-lane slot (2-way across slots = free).
// ---------------------------------------------------------------------------
__global__ __launch_bounds__(512, 4)
void seg_sum_kernel(const float* __restrict__ feats,
                    const int* __restrict__ tgt,
                    const int* __restrict__ lvl,
                    float* __restrict__ sums,     // [NSEG][DIM]
                    float* __restrict__ counts,   // [NSEG]
                    int n, int rowsPerChunk) {
    __shared__ float acc[NSEG * 128];   // [seg][j=0..3][dl4=0..31]
    __shared__ float cntLds[NSEG];

    const int tid  = threadIdx.x;
    const int h    = blockIdx.y;        // dim half: 0 or 1
    const int dl4  = tid & 31;          // float4 index within half
    const int slot = tid >> 5;          // row slot 0..15
    const int S    = 16;                // slots per block

    for (int i = tid; i < NSEG * 128; i += 512) acc[i] = 0.f;
    if (tid < NSEG) cntLds[tid] = 0.f;
    __syncthreads();

    const int base = blockIdx.x * rowsPerChunk;
    int rows = n - base;
    if (rows > rowsPerChunk) rows = rowsPerChunk;
    if (rows < 0) rows = 0;

    const float* fbase = feats + (size_t)base * DIM + h * 128 + dl4 * 4;
    const bool countThread = (h == 0) && (dl4 == 0);

    int r = slot;
    // main unrolled loop: batch UNR loads, then the atomics
    for (; r + (UNR - 1) * S < rows; r += UNR * S) {
        float4 v[UNR];
        int    sg[UNR];
        #pragma unroll
        for (int u = 0; u < UNR; ++u) {
            const int row = r + u * S;
            v[u]  = *reinterpret_cast<const float4*>(fbase + (size_t)row * DIM);
            sg[u] = tgt[base + row] * SCALES + lvl[base + row];
        }
        #pragma unroll
        for (int u = 0; u < UNR; ++u) {
            float* a = &acc[sg[u] * 128 + dl4];
            atomicAdd(a,      v[u].x);
            atomicAdd(a + 32, v[u].y);
            atomicAdd(a + 64, v[u].z);
            atomicAdd(a + 96, v[u].w);
            if (countThread) atomicAdd(&cntLds[sg[u]], 1.f);
        }
    }
    // remainder
    for (; r < rows; r += S) {
        const float4 v = *reinterpret_cast<const float4*>(fbase + (size_t)r * DIM);
        const int   sg = tgt[base + r] * SCALES + lvl[base + r];
        float* a = &acc[sg * 128 + dl4];
        atomicAdd(a,      v.x);
        atomicAdd(a + 32, v.y);
        atomicAdd(a + 64, v.z);
        atomicAdd(a + 96, v.w);
        if (countThread) atomicAdd(&cntLds[sg], 1.f);
    }
    __syncthreads();

    // flush; un-permute [seg][j][dl4] -> dim = h*128 + dl4*4 + j
    for (int i = tid; i < NSEG * 128; i += 512) {
        const int seg = i >> 7;
        const int rem = i & 127;
        const int j   = rem >> 5;
        const int d4  = rem & 31;
        unsafeAtomicAdd(&sums[(size_t)seg * DIM + h * 128 + d4 * 4 + j], acc[i]);
    }
    if (h == 0) {
        for (int i = tid; i < NSEG; i += 512)
            unsafeAtomicAdd(&counts[i], cntLds[i]);
    }
}

// ---------------------------------------------------------------------------
// Kernel 2: InfoNCE head. One block (64 lanes) per output row cs = c*5+s.
// ---------------------------------------------------------------------------
__global__ void infonce_kernel(const float* __restrict__ protos,  // [NSEG][DIM]
                               const float* __restrict__ sums,    // [NSEG][DIM]
                               const float* __restrict__ counts,  // [NSEG]
                               float* __restrict__ numAcc) {
    const int cs   = blockIdx.x;        // c*SCALES + s
    const int s    = cs % SCALES;
    const int lane = threadIdx.x;       // 0..63, 4 dims each

    const float4 p = *reinterpret_cast<const float4*>(
        protos + (size_t)cs * DIM + lane * 4);
    float ssq1 = p.x * p.x + p.y * p.y + p.z * p.z + p.w * p.w;
    #pragma unroll
    for (int off = 32; off > 0; off >>= 1) ssq1 += __shfl_down(ssq1, off);
    ssq1 = __shfl(ssq1, 0);

    float logits[CATS];
    for (int k = 0; k < CATS; ++k) {
        const int r2 = k * SCALES + s;
        const float cntv = counts[r2];
        float4 dv;
        if (cntv > 0.f) {
            const float4 sm = *reinterpret_cast<const float4*>(
                sums + (size_t)r2 * DIM + lane * 4);
            const float inv = 1.f / cntv;
            dv = make_float4(sm.x * inv, sm.y * inv, sm.z * inv, sm.w * inv);
        } else {
            dv = make_float4(0.01f, 0.01f, 0.01f, 0.01f);
        }
        float ssq2 = dv.x * dv.x + dv.y * dv.y + dv.z * dv.z + dv.w * dv.w;
        float dot  = p.x * dv.x + p.y * dv.y + p.z * dv.z + p.w * dv.w;
        #pragma unroll
        for (int off = 32; off > 0; off >>= 1) {
            ssq2 += __shfl_down(ssq2, off);
            dot  += __shfl_down(dot, off);
        }
        const float lg = dot / (sqrtf(ssq2) * sqrtf(ssq1) * TEMP);
        logits[k] = __shfl(lg, 0);
    }

    if (lane == 0) {
        float m = logits[0];
        #pragma unroll
        for (int k = 1; k < CATS; ++k) m = fmaxf(m, logits[k]);
        float sum = 0.f;
        #pragma unroll
        for (int k = 0; k < CATS; ++k) sum += expf(logits[k] - m);
        const float lse     = m + logf(sum);
        const int   label   = cs % CATS;
        const float per_row = lse - logits[label];
        if (counts[cs] > 0.f) unsafeAtomicAdd(numAcc, per_row);
    }
}

// ---------------------------------------------------------------------------
// Kernel 3: final scalar division.
// ---------------------------------------------------------------------------
__global__ void finalize_kernel(const float* __restrict__ counts,
                                const float* __restrict__ numAcc,
                                float* __restrict__ out) {
    float msum = 0.f;
    for (int i = 0; i < NSEG; ++i) msum += (counts[i] > 0.f) ? 1.f : 0.f;
    out[0] = numAcc[0] / fmaxf(msum, 1.f);
}

extern "C" void kernel_launch(void* const* d_in, const int* in_sizes, int n_in,
                              void* d_out, int out_size, void* d_ws, size_t ws_size,
                              hipStream_t stream) {
    const float* feats  = (const float*)d_in[0];   // [N][256] f32
    const int*   tgt    = (const int*)d_in[1];     // [N] int32
    const int*   lvl    = (const int*)d_in[2];     // [N] int32
    const float* protos = (const float*)d_in[3];   // [17][5][256] f32
    float* out = (float*)d_out;

    float* sums   = (float*)d_ws;          // NSEG*DIM
    float* counts = sums + NSEG * DIM;     // NSEG
    float* numAcc = counts + NSEG;         // 1

    const int n = in_sizes[1];             // N rows

    hipMemsetAsync(d_ws, 0, (size_t)(NSEG * DIM + NSEG + 1) * sizeof(float),
                   stream);

    const int nChunks = 384;               // grid 768 = 3 blocks/CU resident
    const int rowsPerChunk = (n + nChunks - 1) / nChunks;
    dim3 g1(nChunks, 2);
    seg_sum_kernel<<<g1, 512, 0, stream>>>(feats, tgt, lvl, sums, counts,
                                           n, rowsPerChunk);
    infonce_kernel<<<NSEG, 64, 0, stream>>>(protos, sums, counts, numAcc);
    finalize_kernel<<<1, 1, 0, stream>>>(counts, numAcc, out);
}

// Round 3
// 276.977 us; speedup vs baseline: 5.3364x; 4.7469x over previous
//
#include <hip/hip_runtime.h>
#include <hip/hip_bf16.h>

#define CATS 17
#define SCALES 5
#define DIM 256
#define NSEG (CATS * SCALES)   // 85
#define TEMP 0.07f
#define P_PARTS 24             // row-range parts per segment; grid = 85*24 = 2040

// ---------------------------------------------------------------------------
// Kernel 1: segment mean via ballot-gather, register-only accumulation.
// One block per (segment g, row-part p). Block = 256 threads = 4 waves.
// Each wave scans 64 labels/iter (coalesced, prefetched), ballots matches,
// and for each match the whole wave loads the 1KB row (64 x float4) and
// accumulates into 4 registers. No LDS, no atomics in the hot loop.
// Same-part blocks (85 consecutive block ids) re-read the same label chunk
// -> L2/L3 resident. Feats are read exactly once, 1KB contiguous bursts.
// ---------------------------------------------------------------------------
__global__ __launch_bounds__(256)
void seg_gather_kernel(const float* __restrict__ feats,
                       const int* __restrict__ tgt,
                       const int* __restrict__ lvl,
                       float* __restrict__ sums,     // [NSEG][DIM]
                       float* __restrict__ counts,   // [NSEG]
                       int n, int rowsPerPart) {
    const int bid  = blockIdx.x;
    const int p    = bid / NSEG;
    const int g    = bid - p * NSEG;        // segment id = c*SCALES + s
    const int c    = g / SCALES;
    const int s    = g - c * SCALES;
    const int t    = threadIdx.x;
    const int lane = t & 63;

    const int rstart = p * rowsPerPart;
    int rend = rstart + rowsPerPart;
    if (rend > n) rend = n;

    float4 acc = make_float4(0.f, 0.f, 0.f, 0.f);
    int myCnt = 0;

    // prefetch first label pair
    int row = rstart + t;
    int tg = -1, lv = -1;
    if (row < rend) { tg = tgt[row]; lv = lvl[row]; }

    for (int r0 = rstart; r0 < rend; r0 += 256) {
        const int rowc = r0 + t;
        const int match = (tg == c) & (lv == s);

        // prefetch next iteration's labels before the gather chain
        const int nr = rowc + 256;
        tg = -1; lv = -1;
        if (nr < rend) { tg = tgt[nr]; lv = lvl[nr]; }

        unsigned long long m = __ballot(match);
        if (lane == 0) myCnt += __popcll(m);
        while (m) {
            const int b = __ffsll((unsigned long long)m) - 1;
            m &= m - 1;
            const int srow = __shfl(rowc, b);   // broadcast matching row id
            const float4 v = *reinterpret_cast<const float4*>(
                feats + (size_t)srow * DIM + lane * 4);
            acc.x += v.x; acc.y += v.y; acc.z += v.z; acc.w += v.w;
        }
    }

    // epilogue: tiny global atomic flush
    float* dst = sums + (size_t)g * DIM + lane * 4;
    unsafeAtomicAdd(dst + 0, acc.x);
    unsafeAtomicAdd(dst + 1, acc.y);
    unsafeAtomicAdd(dst + 2, acc.z);
    unsafeAtomicAdd(dst + 3, acc.w);
    if (lane == 0) unsafeAtomicAdd(&counts[g], (float)myCnt);
}

// ---------------------------------------------------------------------------
// Kernel 2: InfoNCE head. One block (64 lanes) per output row cs = c*5+s.
// ---------------------------------------------------------------------------
__global__ void infonce_kernel(const float* __restrict__ protos,  // [NSEG][DIM]
                               const float* __restrict__ sums,    // [NSEG][DIM]
                               const float* __restrict__ counts,  // [NSEG]
                               float* __restrict__ numAcc) {
    const int cs   = blockIdx.x;        // c*SCALES + s
    const int s    = cs % SCALES;
    const int lane = threadIdx.x;       // 0..63, 4 dims each

    const float4 p = *reinterpret_cast<const float4*>(
        protos + (size_t)cs * DIM + lane * 4);
    float ssq1 = p.x * p.x + p.y * p.y + p.z * p.z + p.w * p.w;
    #pragma unroll
    for (int off = 32; off > 0; off >>= 1) ssq1 += __shfl_down(ssq1, off);
    ssq1 = __shfl(ssq1, 0);

    float logits[CATS];
    for (int k = 0; k < CATS; ++k) {
        const int r2 = k * SCALES + s;
        const float cntv = counts[r2];
        float4 dv;
        if (cntv > 0.f) {
            const float4 sm = *reinterpret_cast<const float4*>(
                sums + (size_t)r2 * DIM + lane * 4);
            const float inv = 1.f / cntv;
            dv = make_float4(sm.x * inv, sm.y * inv, sm.z * inv, sm.w * inv);
        } else {
            dv = make_float4(0.01f, 0.01f, 0.01f, 0.01f);
        }
        float ssq2 = dv.x * dv.x + dv.y * dv.y + dv.z * dv.z + dv.w * dv.w;
        float dot  = p.x * dv.x + p.y * dv.y + p.z * dv.z + p.w * dv.w;
        #pragma unroll
        for (int off = 32; off > 0; off >>= 1) {
            ssq2 += __shfl_down(ssq2, off);
            dot  += __shfl_down(dot, off);
        }
        const float lg = dot / (sqrtf(ssq2) * sqrtf(ssq1) * TEMP);
        logits[k] = __shfl(lg, 0);
    }

    if (lane == 0) {
        float m = logits[0];
        #pragma unroll
        for (int k = 1; k < CATS; ++k) m = fmaxf(m, logits[k]);
        float sum = 0.f;
        #pragma unroll
        for (int k = 0; k < CATS; ++k) sum += expf(logits[k] - m);
        const float lse     = m + logf(sum);
        const int   label   = cs % CATS;
        const float per_row = lse - logits[label];
        if (counts[cs] > 0.f) unsafeAtomicAdd(numAcc, per_row);
    }
}

// ---------------------------------------------------------------------------
// Kernel 3: final scalar division.
// ---------------------------------------------------------------------------
__global__ void finalize_kernel(const float* __restrict__ counts,
                                const float* __restrict__ numAcc,
                                float* __restrict__ out) {
    float msum = 0.f;
    for (int i = 0; i < NSEG; ++i) msum += (counts[i] > 0.f) ? 1.f : 0.f;
    out[0] = numAcc[0] / fmaxf(msum, 1.f);
}

extern "C" void kernel_launch(void* const* d_in, const int* in_sizes, int n_in,
                              void* d_out, int out_size, void* d_ws, size_t ws_size,
                              hipStream_t stream) {
    const float* feats  = (const float*)d_in[0];   // [N][256] f32
    const int*   tgt    = (const int*)d_in[1];     // [N] int32
    const int*   lvl    = (const int*)d_in[2];     // [N] int32
    const float* protos = (const float*)d_in[3];   // [17][5][256] f32
    float* out = (float*)d_out;

    float* sums   = (float*)d_ws;          // NSEG*DIM
    float* counts = sums + NSEG * DIM;     // NSEG
    float* numAcc = counts + NSEG;         // 1

    const int n = in_sizes[1];             // N rows

    hipMemsetAsync(d_ws, 0, (size_t)(NSEG * DIM + NSEG + 1) * sizeof(float),
                   stream);

    const int rowsPerPart = (n + P_PARTS - 1) / P_PARTS;
    seg_gather_kernel<<<NSEG * P_PARTS, 256, 0, stream>>>(
        feats, tgt, lvl, sums, counts, n, rowsPerPart);
    infonce_kernel<<<NSEG, 64, 0, stream>>>(protos, sums, counts, numAcc);
    finalize_kernel<<<1, 1, 0, stream>>>(counts, numAcc, out);
}

// Round 4
// 235.958 us; speedup vs baseline: 6.2641x; 1.1738x over previous
//
#include <hip/hip_runtime.h>
#include <hip/hip_bf16.h>

#define CATS 17
#define SCALES 5
#define DIM 256
#define NSEG (CATS * SCALES)   // 85
#define TEMP 0.07f
#define P_PARTS 24             // row-range parts per segment; grid = 85*24 = 2040

// ---------------------------------------------------------------------------
// Kernel 0: pack seg id = tgt*5+lvl into one byte per row; pad with 0xFF.
// ---------------------------------------------------------------------------
__global__ __launch_bounds__(256)
void pack_kernel(const int* __restrict__ tgt, const int* __restrict__ lvl,
                 unsigned char* __restrict__ seg8, int n, int npad4) {
    const int i = blockIdx.x * 256 + threadIdx.x;   // one uchar4 per thread
    if (i >= npad4) return;
    const int r = i * 4;
    uchar4 o;
    if (r + 3 < n) {
        const int4 t = *reinterpret_cast<const int4*>(tgt + r);
        const int4 l = *reinterpret_cast<const int4*>(lvl + r);
        o.x = (unsigned char)(t.x * SCALES + l.x);
        o.y = (unsigned char)(t.y * SCALES + l.y);
        o.z = (unsigned char)(t.z * SCALES + l.z);
        o.w = (unsigned char)(t.w * SCALES + l.w);
    } else {
        unsigned char b[4];
        #pragma unroll
        for (int k = 0; k < 4; ++k)
            b[k] = (r + k < n) ? (unsigned char)(tgt[r + k] * SCALES + lvl[r + k])
                               : (unsigned char)0xFF;
        o.x = b[0]; o.y = b[1]; o.z = b[2]; o.w = b[3];
    }
    *reinterpret_cast<uchar4*>(seg8 + r) = o;
}

// ---------------------------------------------------------------------------
// Kernel 1: segment mean via ballot-gather over packed seg bytes.
// One block per (segment g, part p); 256 threads = 4 waves.
// Each wave-iter: one uchar4 load per lane covers 256 rows; 4 byte-slot
// ballots; for each set bit the wave loads the 1KB feature row (64 x float4)
// into register accumulators. Row id = r0 + (bit<<2) + w: no shfl needed.
// rowsPerPart is a multiple of 1024 and seg8 is 0xFF-padded -> no bounds
// checks anywhere in the hot loop. No LDS, no atomics in the hot loop.
// ---------------------------------------------------------------------------
__global__ __launch_bounds__(256)
void seg_gather_kernel(const float* __restrict__ feats,
                       const unsigned char* __restrict__ seg8,
                       float* __restrict__ sums,     // [NSEG][DIM]
                       float* __restrict__ counts,   // [NSEG]
                       int rowsPerPart) {
    const int bid  = blockIdx.x;
    const int p    = bid / NSEG;
    const int g    = bid - p * NSEG;        // segment id
    const int t    = threadIdx.x;
    const int lane = t & 63;
    const int wave = t >> 6;

    const int rstart = p * rowsPerPart + wave * 256;
    const int rend   = p * rowsPerPart + rowsPerPart;
    const unsigned char gb = (unsigned char)g;

    float4 acc = make_float4(0.f, 0.f, 0.f, 0.f);
    int cnt = 0;

    const uchar4* sp = reinterpret_cast<const uchar4*>(seg8);

    uchar4 cur = sp[(rstart >> 2) + lane];
    for (int r0 = rstart; r0 < rend; r0 += 1024) {
        const int nr0 = r0 + 1024;
        uchar4 nxt = make_uchar4(0xFF, 0xFF, 0xFF, 0xFF);
        if (nr0 < rend) nxt = sp[(nr0 >> 2) + lane];

        #pragma unroll
        for (int w = 0; w < 4; ++w) {
            const unsigned char b = (w == 0) ? cur.x : (w == 1) ? cur.y
                                  : (w == 2) ? cur.z : cur.w;
            unsigned long long m = __ballot(b == gb);
            cnt += (int)__popcll(m);          // same value on all lanes
            while (m) {
                const int bp = __ffsll((unsigned long long)m) - 1;
                m &= m - 1;
                const int srow = r0 + (bp << 2) + w;
                const float4 v = *reinterpret_cast<const float4*>(
                    feats + (size_t)srow * DIM + lane * 4);
                acc.x += v.x; acc.y += v.y; acc.z += v.z; acc.w += v.w;
            }
        }
        cur = nxt;
    }

    float* dst = sums + (size_t)g * DIM + lane * 4;
    unsafeAtomicAdd(dst + 0, acc.x);
    unsafeAtomicAdd(dst + 1, acc.y);
    unsafeAtomicAdd(dst + 2, acc.z);
    unsafeAtomicAdd(dst + 3, acc.w);
    if (lane == 0) unsafeAtomicAdd(&counts[g], (float)cnt);
}

// ---------------------------------------------------------------------------
// Kernel 2: InfoNCE head. One block (64 lanes) per output row cs = c*5+s.
// ---------------------------------------------------------------------------
__global__ void infonce_kernel(const float* __restrict__ protos,  // [NSEG][DIM]
                               const float* __restrict__ sums,    // [NSEG][DIM]
                               const float* __restrict__ counts,  // [NSEG]
                               float* __restrict__ numAcc) {
    const int cs   = blockIdx.x;        // c*SCALES + s
    const int s    = cs % SCALES;
    const int lane = threadIdx.x;       // 0..63, 4 dims each

    const float4 p = *reinterpret_cast<const float4*>(
        protos + (size_t)cs * DIM + lane * 4);
    float ssq1 = p.x * p.x + p.y * p.y + p.z * p.z + p.w * p.w;
    #pragma unroll
    for (int off = 32; off > 0; off >>= 1) ssq1 += __shfl_down(ssq1, off);
    ssq1 = __shfl(ssq1, 0);

    float logits[CATS];
    for (int k = 0; k < CATS; ++k) {
        const int r2 = k * SCALES + s;
        const float cntv = counts[r2];
        float4 dv;
        if (cntv > 0.f) {
            const float4 sm = *reinterpret_cast<const float4*>(
                sums + (size_t)r2 * DIM + lane * 4);
            const float inv = 1.f / cntv;
            dv = make_float4(sm.x * inv, sm.y * inv, sm.z * inv, sm.w * inv);
        } else {
            dv = make_float4(0.01f, 0.01f, 0.01f, 0.01f);
        }
        float ssq2 = dv.x * dv.x + dv.y * dv.y + dv.z * dv.z + dv.w * dv.w;
        float dot  = p.x * dv.x + p.y * dv.y + p.z * dv.z + p.w * dv.w;
        #pragma unroll
        for (int off = 32; off > 0; off >>= 1) {
            ssq2 += __shfl_down(ssq2, off);
            dot  += __shfl_down(dot, off);
        }
        const float lg = dot / (sqrtf(ssq2) * sqrtf(ssq1) * TEMP);
        logits[k] = __shfl(lg, 0);
    }

    if (lane == 0) {
        float m = logits[0];
        #pragma unroll
        for (int k = 1; k < CATS; ++k) m = fmaxf(m, logits[k]);
        float sum = 0.f;
        #pragma unroll
        for (int k = 0; k < CATS; ++k) sum += expf(logits[k] - m);
        const float lse     = m + logf(sum);
        const int   label   = cs % CATS;
        const float per_row = lse - logits[label];
        if (counts[cs] > 0.f) unsafeAtomicAdd(numAcc, per_row);
    }
}

// ---------------------------------------------------------------------------
// Kernel 3: final scalar division.
// ---------------------------------------------------------------------------
__global__ void finalize_kernel(const float* __restrict__ counts,
                                const float* __restrict__ numAcc,
                                float* __restrict__ out) {
    float msum = 0.f;
    for (int i = 0; i < NSEG; ++i) msum += (counts[i] > 0.f) ? 1.f : 0.f;
    out[0] = numAcc[0] / fmaxf(msum, 1.f);
}

extern "C" void kernel_launch(void* const* d_in, const int* in_sizes, int n_in,
                              void* d_out, int out_size, void* d_ws, size_t ws_size,
                              hipStream_t stream) {
    const float* feats  = (const float*)d_in[0];   // [N][256] f32
    const int*   tgt    = (const int*)d_in[1];     // [N] int32
    const int*   lvl    = (const int*)d_in[2];     // [N] int32
    const float* protos = (const float*)d_in[3];   // [17][5][256] f32
    float* out = (float*)d_out;

    const int n = in_sizes[1];                     // N rows

    // ws layout: sums [NSEG*DIM] | counts [NSEG] | numAcc [1] | pad | seg8
    float* sums   = (float*)d_ws;
    float* counts = sums + NSEG * DIM;
    float* numAcc = counts + NSEG;
    unsigned char* seg8 =
        (unsigned char*)d_ws + (((size_t)(NSEG * DIM + NSEG + 1) * 4 + 127) & ~(size_t)127);

    // rowsPerPart: multiple of 1024 so every wave window is full (0xFF pad)
    int rowsPerPart = (n + P_PARTS - 1) / P_PARTS;
    rowsPerPart = (rowsPerPart + 1023) & ~1023;
    const int npad  = P_PARTS * rowsPerPart;
    const int npad4 = npad / 4;

    hipMemsetAsync(d_ws, 0, (size_t)(NSEG * DIM + NSEG + 1) * sizeof(float),
                   stream);

    pack_kernel<<<(npad4 + 255) / 256, 256, 0, stream>>>(tgt, lvl, seg8, n, npad4);
    seg_gather_kernel<<<NSEG * P_PARTS, 256, 0, stream>>>(
        feats, seg8, sums, counts, rowsPerPart);
    infonce_kernel<<<NSEG, 64, 0, stream>>>(protos, sums, counts, numAcc);
    finalize_kernel<<<1, 1, 0, stream>>>(counts, numAcc, out);
}

// Round 5
// 226.644 us; speedup vs baseline: 6.5215x; 1.0411x over previous
//
#include <hip/hip_runtime.h>
#include <hip/hip_bf16.h>

#define CATS 17
#define SCALES 5
#define DIM 256
#define NSEG (CATS * SCALES)   // 85
#define TEMP 0.07f
#define P_PARTS 24             // row-range parts per segment; grid = 85*24 = 2040

// ---------------------------------------------------------------------------
// Kernel 0: pack seg id = tgt*5+lvl into one byte per row; pad with 0xFF.
// ---------------------------------------------------------------------------
__global__ __launch_bounds__(256)
void pack_kernel(const int* __restrict__ tgt, const int* __restrict__ lvl,
                 unsigned char* __restrict__ seg8, int n, int npad4) {
    const int i = blockIdx.x * 256 + threadIdx.x;   // one uchar4 per thread
    if (i >= npad4) return;
    const int r = i * 4;
    uchar4 o;
    if (r + 3 < n) {
        const int4 t = *reinterpret_cast<const int4*>(tgt + r);
        const int4 l = *reinterpret_cast<const int4*>(lvl + r);
        o.x = (unsigned char)(t.x * SCALES + l.x);
        o.y = (unsigned char)(t.y * SCALES + l.y);
        o.z = (unsigned char)(t.z * SCALES + l.z);
        o.w = (unsigned char)(t.w * SCALES + l.w);
    } else {
        unsigned char b[4];
        #pragma unroll
        for (int k = 0; k < 4; ++k)
            b[k] = (r + k < n) ? (unsigned char)(tgt[r + k] * SCALES + lvl[r + k])
                               : (unsigned char)0xFF;
        o.x = b[0]; o.y = b[1]; o.z = b[2]; o.w = b[3];
    }
    *reinterpret_cast<uchar4*>(seg8 + r) = o;
}

// ---------------------------------------------------------------------------
// Kernel 1: segment mean via ballot-gather, 4-deep batched match loads.
// One block per (segment g, part p); 256 threads = 4 waves.
// Per 256-row window: one uchar4 label load per lane, per-lane 4-bit match
// mask mm, ONE ballot (mm!=0). A wave-uniform SALU state machine pops
// (lane,byte) matches; 4 row ids are popped and their float4 loads issued
// straight-line (empty slots -> dummy L1-resident row-0 load, fma scale 0)
// before any accumulate -> MLP ~= 4 per wave. No LDS, no hot-loop atomics.
// ---------------------------------------------------------------------------
__global__ __launch_bounds__(256)
void seg_gather_kernel(const float* __restrict__ feats,
                       const unsigned char* __restrict__ seg8,
                       float* __restrict__ sums,     // [NSEG][DIM]
                       float* __restrict__ counts,   // [NSEG]
                       int rowsPerPart) {
    const int bid  = blockIdx.x;
    const int p    = bid / NSEG;
    const int g    = bid - p * NSEG;        // segment id
    const int t    = threadIdx.x;
    const int lane = t & 63;
    const int wave = t >> 6;

    const int rstart = p * rowsPerPart + wave * 256;
    const int rend   = p * rowsPerPart + rowsPerPart;
    const unsigned char gb = (unsigned char)g;

    float4 acc0 = make_float4(0.f, 0.f, 0.f, 0.f);
    float4 acc1 = make_float4(0.f, 0.f, 0.f, 0.f);
    float4 acc2 = make_float4(0.f, 0.f, 0.f, 0.f);
    float4 acc3 = make_float4(0.f, 0.f, 0.f, 0.f);
    int cntLoc = 0;

    const uchar4* sp = reinterpret_cast<const uchar4*>(seg8);

    uchar4 cur = sp[(rstart >> 2) + lane];
    for (int r0 = rstart; r0 < rend; r0 += 1024) {
        const int nr0 = r0 + 1024;
        uchar4 nxt = make_uchar4(0xFF, 0xFF, 0xFF, 0xFF);
        if (nr0 < rend) nxt = sp[(nr0 >> 2) + lane];

        const unsigned mm = (cur.x == gb ? 1u : 0u) | (cur.y == gb ? 2u : 0u)
                          | (cur.z == gb ? 4u : 0u) | (cur.w == gb ? 8u : 0u);
        cntLoc += __popc(mm);
        unsigned long long m = __ballot(mm != 0u);

        // wave-uniform match-stream state machine
        unsigned mb = 0u;     // current lane's remaining byte mask (uniform)
        int basec = 0;        // current lane's base row (uniform)
        auto pop = [&]() -> int {
            for (;;) {
                if (mb) { const int j = __ffs((int)mb) - 1; mb &= mb - 1u;
                          return basec + j; }
                if (!m) return -1;
                const int b = __ffsll((unsigned long long)m) - 1; m &= m - 1;
                mb = __shfl(mm, b);           // uniform: lane b's byte mask
                basec = r0 + (b << 2);
            }
        };

        int rA = pop();
        while (rA >= 0) {
            const int rB = pop();
            const int rC = (rB >= 0) ? pop() : -1;
            const int rD = (rC >= 0) ? pop() : -1;
            // branchless: clamp negative ids to row 0 (L1-resident dummy)
            const int ra = rA & ~(rA >> 31);
            const int rb = rB & ~(rB >> 31);
            const int rc = rC & ~(rC >> 31);
            const int rd = rD & ~(rD >> 31);
            const float4 vA = *reinterpret_cast<const float4*>(
                feats + (size_t)ra * DIM + lane * 4);
            const float4 vB = *reinterpret_cast<const float4*>(
                feats + (size_t)rb * DIM + lane * 4);
            const float4 vC = *reinterpret_cast<const float4*>(
                feats + (size_t)rc * DIM + lane * 4);
            const float4 vD = *reinterpret_cast<const float4*>(
                feats + (size_t)rd * DIM + lane * 4);
            const float sB = (rB >= 0) ? 1.f : 0.f;
            const float sC = (rC >= 0) ? 1.f : 0.f;
            const float sD = (rD >= 0) ? 1.f : 0.f;
            acc0.x += vA.x; acc0.y += vA.y; acc0.z += vA.z; acc0.w += vA.w;
            acc1.x = fmaf(vB.x, sB, acc1.x); acc1.y = fmaf(vB.y, sB, acc1.y);
            acc1.z = fmaf(vB.z, sB, acc1.z); acc1.w = fmaf(vB.w, sB, acc1.w);
            acc2.x = fmaf(vC.x, sC, acc2.x); acc2.y = fmaf(vC.y, sC, acc2.y);
            acc2.z = fmaf(vC.z, sC, acc2.z); acc2.w = fmaf(vC.w, sC, acc2.w);
            acc3.x = fmaf(vD.x, sD, acc3.x); acc3.y = fmaf(vD.y, sD, acc3.y);
            acc3.z = fmaf(vD.z, sD, acc3.z); acc3.w = fmaf(vD.w, sD, acc3.w);
            rA = (rD >= 0) ? pop() : -1;
        }
        cur = nxt;
    }

    acc0.x += acc1.x + acc2.x + acc3.x;
    acc0.y += acc1.y + acc2.y + acc3.y;
    acc0.z += acc1.z + acc2.z + acc3.z;
    acc0.w += acc1.w + acc2.w + acc3.w;

    float* dst = sums + (size_t)g * DIM + lane * 4;
    unsafeAtomicAdd(dst + 0, acc0.x);
    unsafeAtomicAdd(dst + 1, acc0.y);
    unsafeAtomicAdd(dst + 2, acc0.z);
    unsafeAtomicAdd(dst + 3, acc0.w);

    #pragma unroll
    for (int off = 32; off > 0; off >>= 1) cntLoc += __shfl_down(cntLoc, off);
    if (lane == 0) unsafeAtomicAdd(&counts[g], (float)cntLoc);
}

// ---------------------------------------------------------------------------
// Kernel 2: InfoNCE head. One block (64 lanes) per output row cs = c*5+s.
// ---------------------------------------------------------------------------
__global__ void infonce_kernel(const float* __restrict__ protos,  // [NSEG][DIM]
                               const float* __restrict__ sums,    // [NSEG][DIM]
                               const float* __restrict__ counts,  // [NSEG]
                               float* __restrict__ numAcc) {
    const int cs   = blockIdx.x;        // c*SCALES + s
    const int s    = cs % SCALES;
    const int lane = threadIdx.x;       // 0..63, 4 dims each

    const float4 p = *reinterpret_cast<const float4*>(
        protos + (size_t)cs * DIM + lane * 4);
    float ssq1 = p.x * p.x + p.y * p.y + p.z * p.z + p.w * p.w;
    #pragma unroll
    for (int off = 32; off > 0; off >>= 1) ssq1 += __shfl_down(ssq1, off);
    ssq1 = __shfl(ssq1, 0);

    float logits[CATS];
    for (int k = 0; k < CATS; ++k) {
        const int r2 = k * SCALES + s;
        const float cntv = counts[r2];
        float4 dv;
        if (cntv > 0.f) {
            const float4 sm = *reinterpret_cast<const float4*>(
                sums + (size_t)r2 * DIM + lane * 4);
            const float inv = 1.f / cntv;
            dv = make_float4(sm.x * inv, sm.y * inv, sm.z * inv, sm.w * inv);
        } else {
            dv = make_float4(0.01f, 0.01f, 0.01f, 0.01f);
        }
        float ssq2 = dv.x * dv.x + dv.y * dv.y + dv.z * dv.z + dv.w * dv.w;
        float dot  = p.x * dv.x + p.y * dv.y + p.z * dv.z + p.w * dv.w;
        #pragma unroll
        for (int off = 32; off > 0; off >>= 1) {
            ssq2 += __shfl_down(ssq2, off);
            dot  += __shfl_down(dot, off);
        }
        const float lg = dot / (sqrtf(ssq2) * sqrtf(ssq1) * TEMP);
        logits[k] = __shfl(lg, 0);
    }

    if (lane == 0) {
        float m = logits[0];
        #pragma unroll
        for (int k = 1; k < CATS; ++k) m = fmaxf(m, logits[k]);
        float sum = 0.f;
        #pragma unroll
        for (int k = 0; k < CATS; ++k) sum += expf(logits[k] - m);
        const float lse     = m + logf(sum);
        const int   label   = cs % CATS;
        const float per_row = lse - logits[label];
        if (counts[cs] > 0.f) unsafeAtomicAdd(numAcc, per_row);
    }
}

// ---------------------------------------------------------------------------
// Kernel 3: final scalar division.
// ---------------------------------------------------------------------------
__global__ void finalize_kernel(const float* __restrict__ counts,
                                const float* __restrict__ numAcc,
                                float* __restrict__ out) {
    float msum = 0.f;
    for (int i = 0; i < NSEG; ++i) msum += (counts[i] > 0.f) ? 1.f : 0.f;
    out[0] = numAcc[0] / fmaxf(msum, 1.f);
}

extern "C" void kernel_launch(void* const* d_in, const int* in_sizes, int n_in,
                              void* d_out, int out_size, void* d_ws, size_t ws_size,
                              hipStream_t stream) {
    const float* feats  = (const float*)d_in[0];   // [N][256] f32
    const int*   tgt    = (const int*)d_in[1];     // [N] int32
    const int*   lvl    = (const int*)d_in[2];     // [N] int32
    const float* protos = (const float*)d_in[3];   // [17][5][256] f32
    float* out = (float*)d_out;

    const int n = in_sizes[1];                     // N rows

    // ws layout: sums [NSEG*DIM] | counts [NSEG] | numAcc [1] | pad | seg8
    float* sums   = (float*)d_ws;
    float* counts = sums + NSEG * DIM;
    float* numAcc = counts + NSEG;
    unsigned char* seg8 =
        (unsigned char*)d_ws + (((size_t)(NSEG * DIM + NSEG + 1) * 4 + 127) & ~(size_t)127);

    // rowsPerPart: multiple of 1024 so every wave window is full (0xFF pad)
    int rowsPerPart = (n + P_PARTS - 1) / P_PARTS;
    rowsPerPart = (rowsPerPart + 1023) & ~1023;
    const int npad  = P_PARTS * rowsPerPart;
    const int npad4 = npad / 4;

    hipMemsetAsync(d_ws, 0, (size_t)(NSEG * DIM + NSEG + 1) * sizeof(float),
                   stream);

    pack_kernel<<<(npad4 + 255) / 256, 256, 0, stream>>>(tgt, lvl, seg8, n, npad4);
    seg_gather_kernel<<<NSEG * P_PARTS, 256, 0, stream>>>(
        feats, seg8, sums, counts, rowsPerPart);
    infonce_kernel<<<NSEG, 64, 0, stream>>>(protos, sums, counts, numAcc);
    finalize_kernel<<<1, 1, 0, stream>>>(counts, numAcc, out);
}

// Round 6
// 218.411 us; speedup vs baseline: 6.7674x; 1.0377x over previous
//
#include <hip/hip_runtime.h>
#include <hip/hip_bf16.h>

#define CATS 17
#define SCALES 5
#define DIM 256
#define NSEG (CATS * SCALES)   // 85
#define TEMP 0.07f
#define GPARTS 12              // gather blocks per segment: grid = 85*12 = 1020
#define CHUNK_ROWS 4096        // rows per build block (256 thr x 16)

// ---------------------------------------------------------------------------
// Kernel 0: build compact per-segment row-id lists.
// Per block: LDS histogram over 4096 rows, one global atomicAdd per (block,
// seg) reserves a slot range, LDS rank counters assign slots, scatter ids.
// ---------------------------------------------------------------------------
__global__ __launch_bounds__(256)
void build_kernel(const int* __restrict__ tgt, const int* __restrict__ lvl,
                  int* __restrict__ idx, int* __restrict__ gCnt,
                  int n, int idxStride) {
    __shared__ int hist[NSEG];
    __shared__ int baseb[NSEG];

    const int t  = threadIdx.x;
    const int r0 = blockIdx.x * CHUNK_ROWS;
    const int rbase = r0 + t * 16;

    for (int i = t; i < NSEG; i += 256) hist[i] = 0;
    __syncthreads();

    int segv[16];
    if (rbase + 16 <= n) {
        #pragma unroll
        for (int q = 0; q < 4; ++q) {
            const int4 tv = *reinterpret_cast<const int4*>(tgt + rbase + q * 4);
            const int4 lv = *reinterpret_cast<const int4*>(lvl + rbase + q * 4);
            segv[q * 4 + 0] = tv.x * SCALES + lv.x;
            segv[q * 4 + 1] = tv.y * SCALES + lv.y;
            segv[q * 4 + 2] = tv.z * SCALES + lv.z;
            segv[q * 4 + 3] = tv.w * SCALES + lv.w;
        }
    } else {
        #pragma unroll
        for (int k = 0; k < 16; ++k)
            segv[k] = (rbase + k < n)
                    ? tgt[rbase + k] * SCALES + lvl[rbase + k] : -1;
    }

    #pragma unroll
    for (int k = 0; k < 16; ++k)
        if (segv[k] >= 0) atomicAdd(&hist[segv[k]], 1);
    __syncthreads();

    for (int i = t; i < NSEG; i += 256)
        baseb[i] = atomicAdd(&gCnt[i], hist[i]);
    __syncthreads();
    for (int i = t; i < NSEG; i += 256) hist[i] = 0;   // reuse as rank ctrs
    __syncthreads();

    #pragma unroll
    for (int k = 0; k < 16; ++k) {
        const int s = segv[k];
        if (s >= 0) {
            const int rk = atomicAdd(&hist[s], 1);
            idx[(size_t)s * idxStride + baseb[s] + rk] = rbase + k;
        }
    }
}

// ---------------------------------------------------------------------------
// Kernel 1: pure streaming gather. Block (g,p): 256 threads = 4 waves.
// Each wave loads 64 row ids with one coalesced dword load, then streams the
// 1KB feature rows 8-deep (all loads real; ragged tails clamp the id and
// fma with scale 0). Register-only accumulation; tiny atomic flush.
// ---------------------------------------------------------------------------
__global__ __launch_bounds__(256)
void gather_kernel(const float* __restrict__ feats,
                   const int* __restrict__ idx,
                   const int* __restrict__ gCnt,
                   float* __restrict__ sums,     // [NSEG][DIM]
                   int idxStride) {
    const int bid  = blockIdx.x;
    const int g    = bid / GPARTS;
    const int p    = bid - g * GPARTS;
    const int lane = threadIdx.x & 63;
    const int wave = threadIdx.x >> 6;

    const int cnt   = gCnt[g];
    const int chunk = (cnt + GPARTS - 1) / GPARTS;
    const int e0    = p * chunk;
    const int e1    = min(e0 + chunk, cnt);
    const int* lst  = idx + (size_t)g * idxStride;

    float4 a0 = make_float4(0.f, 0.f, 0.f, 0.f), a1 = a0, a2 = a0, a3 = a0;
    float4 a4 = a0, a5 = a0, a6 = a0, a7 = a0;

    for (int e = e0 + wave * 64; e < e1; e += 256) {
        const int cntHere = min(64, e1 - e);
        const int ridv = lst[e + ((lane < cntHere) ? lane : 0)];

        if (cntHere == 64) {
            #pragma unroll
            for (int j0 = 0; j0 < 64; j0 += 8) {
                float4 v[8];
                #pragma unroll
                for (int u = 0; u < 8; ++u) {
                    const int sr = __shfl(ridv, j0 + u);
                    v[u] = *reinterpret_cast<const float4*>(
                        feats + (size_t)sr * DIM + lane * 4);
                }
                a0.x += v[0].x; a0.y += v[0].y; a0.z += v[0].z; a0.w += v[0].w;
                a1.x += v[1].x; a1.y += v[1].y; a1.z += v[1].z; a1.w += v[1].w;
                a2.x += v[2].x; a2.y += v[2].y; a2.z += v[2].z; a2.w += v[2].w;
                a3.x += v[3].x; a3.y += v[3].y; a3.z += v[3].z; a3.w += v[3].w;
                a4.x += v[4].x; a4.y += v[4].y; a4.z += v[4].z; a4.w += v[4].w;
                a5.x += v[5].x; a5.y += v[5].y; a5.z += v[5].z; a5.w += v[5].w;
                a6.x += v[6].x; a6.y += v[6].y; a6.z += v[6].z; a6.w += v[6].w;
                a7.x += v[7].x; a7.y += v[7].y; a7.z += v[7].z; a7.w += v[7].w;
            }
        } else {
            for (int j0 = 0; j0 < cntHere; j0 += 8) {
                float4 v[8]; float sc[8];
                #pragma unroll
                for (int u = 0; u < 8; ++u) {
                    const int jj = j0 + u;
                    const int jc = (jj < cntHere) ? jj : (cntHere - 1);
                    sc[u] = (jj < cntHere) ? 1.f : 0.f;
                    const int sr = __shfl(ridv, jc);
                    v[u] = *reinterpret_cast<const float4*>(
                        feats + (size_t)sr * DIM + lane * 4);
                }
                a0.x = fmaf(v[0].x, sc[0], a0.x); a0.y = fmaf(v[0].y, sc[0], a0.y);
                a0.z = fmaf(v[0].z, sc[0], a0.z); a0.w = fmaf(v[0].w, sc[0], a0.w);
                a1.x = fmaf(v[1].x, sc[1], a1.x); a1.y = fmaf(v[1].y, sc[1], a1.y);
                a1.z = fmaf(v[1].z, sc[1], a1.z); a1.w = fmaf(v[1].w, sc[1], a1.w);
                a2.x = fmaf(v[2].x, sc[2], a2.x); a2.y = fmaf(v[2].y, sc[2], a2.y);
                a2.z = fmaf(v[2].z, sc[2], a2.z); a2.w = fmaf(v[2].w, sc[2], a2.w);
                a3.x = fmaf(v[3].x, sc[3], a3.x); a3.y = fmaf(v[3].y, sc[3], a3.y);
                a3.z = fmaf(v[3].z, sc[3], a3.z); a3.w = fmaf(v[3].w, sc[3], a3.w);
                a4.x = fmaf(v[4].x, sc[4], a4.x); a4.y = fmaf(v[4].y, sc[4], a4.y);
                a4.z = fmaf(v[4].z, sc[4], a4.z); a4.w = fmaf(v[4].w, sc[4], a4.w);
                a5.x = fmaf(v[5].x, sc[5], a5.x); a5.y = fmaf(v[5].y, sc[5], a5.y);
                a5.z = fmaf(v[5].z, sc[5], a5.z); a5.w = fmaf(v[5].w, sc[5], a5.w);
                a6.x = fmaf(v[6].x, sc[6], a6.x); a6.y = fmaf(v[6].y, sc[6], a6.y);
                a6.z = fmaf(v[6].z, sc[6], a6.z); a6.w = fmaf(v[6].w, sc[6], a6.w);
                a7.x = fmaf(v[7].x, sc[7], a7.x); a7.y = fmaf(v[7].y, sc[7], a7.y);
                a7.z = fmaf(v[7].z, sc[7], a7.z); a7.w = fmaf(v[7].w, sc[7], a7.w);
            }
        }
    }

    a0.x += a1.x + a2.x + a3.x + a4.x + a5.x + a6.x + a7.x;
    a0.y += a1.y + a2.y + a3.y + a4.y + a5.y + a6.y + a7.y;
    a0.z += a1.z + a2.z + a3.z + a4.z + a5.z + a6.z + a7.z;
    a0.w += a1.w + a2.w + a3.w + a4.w + a5.w + a6.w + a7.w;

    float* dst = sums + (size_t)g * DIM + lane * 4;
    unsafeAtomicAdd(dst + 0, a0.x);
    unsafeAtomicAdd(dst + 1, a0.y);
    unsafeAtomicAdd(dst + 2, a0.z);
    unsafeAtomicAdd(dst + 3, a0.w);
}

// ---------------------------------------------------------------------------
// Kernel 2: InfoNCE head. One block (64 lanes) per output row cs = c*5+s.
// ---------------------------------------------------------------------------
__global__ void infonce_kernel(const float* __restrict__ protos,  // [NSEG][DIM]
                               const float* __restrict__ sums,    // [NSEG][DIM]
                               const int* __restrict__ gCnt,      // [NSEG]
                               float* __restrict__ numAcc) {
    const int cs   = blockIdx.x;        // c*SCALES + s
    const int s    = cs % SCALES;
    const int lane = threadIdx.x;       // 0..63, 4 dims each

    const float4 p = *reinterpret_cast<const float4*>(
        protos + (size_t)cs * DIM + lane * 4);
    float ssq1 = p.x * p.x + p.y * p.y + p.z * p.z + p.w * p.w;
    #pragma unroll
    for (int off = 32; off > 0; off >>= 1) ssq1 += __shfl_down(ssq1, off);
    ssq1 = __shfl(ssq1, 0);

    float logits[CATS];
    for (int k = 0; k < CATS; ++k) {
        const int r2 = k * SCALES + s;
        const int cntv = gCnt[r2];
        float4 dv;
        if (cntv > 0) {
            const float4 sm = *reinterpret_cast<const float4*>(
                sums + (size_t)r2 * DIM + lane * 4);
            const float inv = 1.f / (float)cntv;
            dv = make_float4(sm.x * inv, sm.y * inv, sm.z * inv, sm.w * inv);
        } else {
            dv = make_float4(0.01f, 0.01f, 0.01f, 0.01f);
        }
        float ssq2 = dv.x * dv.x + dv.y * dv.y + dv.z * dv.z + dv.w * dv.w;
        float dot  = p.x * dv.x + p.y * dv.y + p.z * dv.z + p.w * dv.w;
        #pragma unroll
        for (int off = 32; off > 0; off >>= 1) {
            ssq2 += __shfl_down(ssq2, off);
            dot  += __shfl_down(dot, off);
        }
        const float lg = dot / (sqrtf(ssq2) * sqrtf(ssq1) * TEMP);
        logits[k] = __shfl(lg, 0);
    }

    if (lane == 0) {
        float m = logits[0];
        #pragma unroll
        for (int k = 1; k < CATS; ++k) m = fmaxf(m, logits[k]);
        float sum = 0.f;
        #pragma unroll
        for (int k = 0; k < CATS; ++k) sum += expf(logits[k] - m);
        const float lse     = m + logf(sum);
        const int   label   = cs % CATS;
        const float per_row = lse - logits[label];
        if (gCnt[cs] > 0) unsafeAtomicAdd(numAcc, per_row);
    }
}

// ---------------------------------------------------------------------------
// Kernel 3: final scalar division.
// ---------------------------------------------------------------------------
__global__ void finalize_kernel(const int* __restrict__ gCnt,
                                const float* __restrict__ numAcc,
                                float* __restrict__ out) {
    float msum = 0.f;
    for (int i = 0; i < NSEG; ++i) msum += (gCnt[i] > 0) ? 1.f : 0.f;
    out[0] = numAcc[0] / fmaxf(msum, 1.f);
}

extern "C" void kernel_launch(void* const* d_in, const int* in_sizes, int n_in,
                              void* d_out, int out_size, void* d_ws, size_t ws_size,
                              hipStream_t stream) {
    const float* feats  = (const float*)d_in[0];   // [N][256] f32
    const int*   tgt    = (const int*)d_in[1];     // [N] int32
    const int*   lvl    = (const int*)d_in[2];     // [N] int32
    const float* protos = (const float*)d_in[3];   // [17][5][256] f32
    float* out = (float*)d_out;

    const int n = in_sizes[1];                     // N rows

    // ws layout: sums [NSEG*DIM] | numAcc [1] | gCnt [NSEG] | pad | idx [NSEG*n]
    float* sums   = (float*)d_ws;
    float* numAcc = sums + NSEG * DIM;
    int*   gCnt   = (int*)(numAcc + 1);
    const size_t smallBytes = (size_t)(NSEG * DIM + 1 + NSEG) * 4;
    int* idx = (int*)((char*)d_ws + ((smallBytes + 127) & ~(size_t)127));

    hipMemsetAsync(d_ws, 0, smallBytes, stream);

    const int nBuild = (n + CHUNK_ROWS - 1) / CHUNK_ROWS;
    build_kernel<<<nBuild, 256, 0, stream>>>(tgt, lvl, idx, gCnt, n, n);
    gather_kernel<<<NSEG * GPARTS, 256, 0, stream>>>(feats, idx, gCnt, sums, n);
    infonce_kernel<<<NSEG, 64, 0, stream>>>(protos, sums, gCnt, numAcc);
    finalize_kernel<<<1, 1, 0, stream>>>(gCnt, numAcc, out);
}